// Round 12
// baseline (194.258 us; speedup 1.0000x reference)
//
#include <hip/hip_runtime.h>
#include <hip/hip_fp16.h>
#include <math.h>

// Fixed-capacity bucketed CSR build (per-tile LDS counting sort -> coalesced
// bucket writes), then node-parallel coalesced gather aggregation with fp16
// gather tables (hw1h 3.2 MB, hw2h 1.6 MB).
// R1: wave-shuffle scans. R3: quad-split agg. R5: masked tails + idx prefetch.
// R10: LDS-staged sortbucket scatter (-10.8). R11: rank capture (-2.5).
// R12: PIPELINE REORDER for L2 residency. R4's agg1c profile showed FETCH
//     32 MB >> working set: gemm1's 51 MB x-stream ran between sortbucket
//     and agg1c, evicting csr_src + hw1h. Now gemm1 (UNSCALED x@W1) runs
//     FIRST; sortbucket scales hw1h rows in its epilogue (it already knows
//     each node's degree). Nothing big streams between the CSR build and
//     the gather kernels -> csr_src + tables stay cache-warm.
#define BSHIFT 8
#define BUCK   256
#define TILE   8192     // edges per scatter workgroup (1024 threads, 8 edges/thread)
#define CAP    12288    // bucket capacity; mean 8184, sigma 90 -> 45 sigma headroom

typedef _Float16 f16x2 __attribute__((ext_vector_type(2)));
typedef _Float16 f16x4 __attribute__((ext_vector_type(4)));
typedef _Float16 f16x8 __attribute__((ext_vector_type(8)));
typedef float    f32x4 __attribute__((ext_vector_type(4)));

// ---------------- CSR build ----------------

__global__ __launch_bounds__(256) void k_curinit(int* __restrict__ bcursor, int nbuk) {
    int b = blockIdx.x * 256 + threadIdx.x;
    if (b < nbuk) bcursor[b] = b * CAP;
}

// tile scatter with full per-tile LDS counting sort by bucket, so the global
// binned[] writes are lane-consecutive (coalesced bursts per bucket run).
// packed edge = (dst&255)<<17 | src   (src < 2^17)
// R11: single atomic pass — histogram atomicAdd returns per-edge rank.
__global__ __launch_bounds__(1024) void k_binscatter(const int* __restrict__ src,
                                                     const int* __restrict__ dst,
                                                     int* __restrict__ bcursor,
                                                     int* __restrict__ binned, int E, int nbuk) {
    __shared__ int            payload[TILE];   // 32 KB
    __shared__ unsigned short bid16[TILE];     // 16 KB
    __shared__ int cnt[512];                   // histogram
    __shared__ int lstart[512];                // exclusive scan (local base)
    __shared__ int gbase[512];                 // reserved global base
    __shared__ int wsum[8];
    int t = threadIdx.x;
    int tile0 = blockIdx.x * TILE;
    int tileE = min(TILE, E - tile0);
    if (t < 512) cnt[t] = 0;
    __syncthreads();
    // load 8 edges/thread (vectorized when full)
    int d[8], s[8];
    int base = t * 8;
    if (base + 8 <= tileE) {
        const int4* d4 = (const int4*)(dst + tile0 + base);
        const int4* s4 = (const int4*)(src + tile0 + base);
        int4 da = d4[0], db = d4[1];
        int4 sa = s4[0], sb = s4[1];
        d[0] = da.x; d[1] = da.y; d[2] = da.z; d[3] = da.w;
        d[4] = db.x; d[5] = db.y; d[6] = db.z; d[7] = db.w;
        s[0] = sa.x; s[1] = sa.y; s[2] = sa.z; s[3] = sa.w;
        s[4] = sb.x; s[5] = sb.y; s[6] = sb.z; s[7] = sb.w;
    } else {
#pragma unroll
        for (int q = 0; q < 8; ++q) {
            int idx = base + q;
            if (idx < tileE) { d[q] = dst[tile0 + idx]; s[q] = src[tile0 + idx]; }
            else d[q] = -1;
        }
    }
    int rank[8];                               // rank within bucket (free!)
#pragma unroll
    for (int q = 0; q < 8; ++q)
        if (d[q] >= 0) rank[q] = atomicAdd(&cnt[d[q] >> BSHIFT], 1);
    __syncthreads();
    // wave-shuffle exclusive scan over cnt[512]: 8 full waves scan 64 each,
    // thread 0 combines wave sums.
    int c = 0, ex = 0;
    if (t < 512) {
        c = cnt[t];
        int v = c;
#pragma unroll
        for (int off = 1; off < 64; off <<= 1) {
            int u = __shfl_up(v, off, 64);
            if ((t & 63) >= off) v += u;
        }
        if ((t & 63) == 63) wsum[t >> 6] = v;
        ex = v - c;
    }
    __syncthreads();
    if (t == 0) {
        int run = 0;
#pragma unroll
        for (int w = 0; w < 8; ++w) { int u = wsum[w]; wsum[w] = run; run += u; }
    }
    __syncthreads();
    if (t < 512) {
        ex += wsum[t >> 6];
        gbase[t] = c ? atomicAdd(&bcursor[t], c) : 0;   // reserve global run
        lstart[t] = ex;                                  // local base
    }
    __syncthreads();
    // LDS scatter WITHOUT atomics: position = lstart[b] + rank
#pragma unroll
    for (int q = 0; q < 8; ++q) {
        if (d[q] >= 0) {
            int b = d[q] >> BSHIFT;
            int lp = lstart[b] + rank[q];
            payload[lp] = ((d[q] & (BUCK - 1)) << 17) | s[q];
            bid16[lp] = (unsigned short)b;
        }
    }
    __syncthreads();
    // coalesced copy-out: consecutive k -> consecutive global addresses
    for (int k = t; k < tileE; k += 1024) {
        int b = bid16[k];
        int ga = gbase[b] + (k - lstart[b]);
        if (ga < (b + 1) * CAP)                          // overflow guard (45 sigma)
            binned[ga] = payload[k];
    }
}

// per-bucket counting sort -> csr_src (dst-sorted, sparse layout), rowstart/
// rowend, dinv. R10: LDS-staged scatter + coalesced copy-out. R11: rank
// capture. R12: epilogue scales hw1h rows by dinv (gemm1 now runs first,
// unscaled) — keeps the x-stream away from the gather kernels' cache state.
__global__ __launch_bounds__(1024) void k_sortbucket(const int* __restrict__ bcursor,
                                                     const int* __restrict__ binned,
                                                     int* __restrict__ csr_src,
                                                     int* __restrict__ rowstart,
                                                     int* __restrict__ rowend,
                                                     float* __restrict__ dinv,
                                                     __half* __restrict__ hw1h, int N) {
    __shared__ int sp[CAP];          // 48 KB sorted payload stage
    __shared__ int cnt[BUCK];
    __shared__ int excl[BUCK];
    __shared__ int wsum[4];
    int b = blockIdx.x, t = threadIdx.x;
    if (t < BUCK) cnt[t] = 0;
    __syncthreads();
    int beg = b * CAP;
    int end = min(bcursor[b], beg + CAP);
    int tot = end - beg;
    int v[12];
#pragma unroll
    for (int q = 0; q < 12; ++q) {
        int e = beg + q * 1024 + t;
        v[q] = (e < end) ? binned[e] : -1;
    }
    int rk[12];                      // rank within node (free from histogram)
#pragma unroll
    for (int q = 0; q < 12; ++q)
        if (v[q] >= 0) rk[q] = atomicAdd(&cnt[v[q] >> 17], 1);
    __syncthreads();
    // wave-shuffle exclusive scan over cnt[256] (4 full waves + combine)
    int c = 0, ex = 0;
    if (t < BUCK) {
        c = cnt[t];
        int s = c;
#pragma unroll
        for (int off = 1; off < 64; off <<= 1) {
            int u = __shfl_up(s, off, 64);
            if ((t & 63) >= off) s += u;
        }
        if ((t & 63) == 63) wsum[t >> 6] = s;
        ex = s - c;
    }
    __syncthreads();
    if (t == 0) {
        int run = 0;
#pragma unroll
        for (int w = 0; w < 4; ++w) { int u = wsum[w]; wsum[w] = run; run += u; }
    }
    __syncthreads();
    if (t < BUCK) {
        ex += wsum[t >> 6];
        excl[t] = ex;
        int node = b * BUCK + t;
        if (node < N) {
            rowstart[node] = beg + ex;
            rowend[node]   = beg + ex + c;
            float di = rsqrtf((float)(c + 1));   // +1 self loop
            dinv[node] = di;
            // R12: scale this node's hw1h row in place (gemm1 wrote unscaled)
            f16x8* row = (f16x8*)&hw1h[(size_t)node * 16];
            f16x8 lo = row[0], hi = row[1];
            _Float16 dh = (_Float16)di;
#pragma unroll
            for (int d = 0; d < 8; ++d) { lo[d] = lo[d] * dh; hi[d] = hi[d] * dh; }
            row[0] = lo; row[1] = hi;
        }
    }
    __syncthreads();
    // LDS scatter WITHOUT atomics: pos = excl[node] + rank
#pragma unroll
    for (int q = 0; q < 12; ++q) {
        if (v[q] >= 0) {
            int pos = excl[v[q] >> 17] + rk[q];
            sp[pos] = v[q] & 0x1FFFF;              // pos < tot <= CAP
        }
    }
    __syncthreads();
    for (int k = t; k < tot; k += 1024)            // coalesced copy-out
        csr_src[beg + k] = sp[k];
}

// ---------------- layer compute ----------------

// hw1h[i,:] = fp16( x[i,:] @ W1 )  UNSCALED via MFMA 16x16x32 f16.
// (dinv scaling applied later by sortbucket's epilogue.)
__global__ __launch_bounds__(256) void k_gemm1(const float* __restrict__ x,
                                               const float* __restrict__ W1,
                                               __half* __restrict__ hw1h, int N) {
    __shared__ _Float16 sX[64 * 136];   // x tile fp16, row pad 136
    __shared__ _Float16 sW[16 * 136];   // W1^T fp16
    __shared__ _Float16 sOut[64 * 16];
    int t = threadIdx.x;
    int row0 = blockIdx.x * 64;
    for (int e = t; e < 2048; e += 256) {
        int n = e & 15, k = e >> 4;
        sW[n * 136 + k] = (_Float16)W1[k * 16 + n];
    }
    const float4* x4 = (const float4*)x;
#pragma unroll
    for (int q = 0; q < 8; ++q) {
        int e = q * 256 + t;
        int r = e >> 5, c4 = e & 31;
        int gr = row0 + r;
        float4 v = (gr < N) ? x4[(size_t)gr * 32 + c4] : make_float4(0.f, 0.f, 0.f, 0.f);
        f16x4 hv = {(_Float16)v.x, (_Float16)v.y, (_Float16)v.z, (_Float16)v.w};
        *(f16x4*)&sX[r * 136 + c4 * 4] = hv;   // one ds_write_b64 (8B-aligned)
    }
    __syncthreads();
    int w = t >> 6, l = t & 63;
    int m = l & 15, quad = l >> 4;
    f32x4 acc = {0.f, 0.f, 0.f, 0.f};
#pragma unroll
    for (int kc = 0; kc < 4; ++kc) {
        f16x8 a = *(const f16x8*)&sX[(w * 16 + m) * 136 + kc * 32 + quad * 8];
        f16x8 b = *(const f16x8*)&sW[m * 136 + kc * 32 + quad * 8];
        acc = __builtin_amdgcn_mfma_f32_16x16x32_f16(a, b, acc, 0, 0, 0);
    }
#pragma unroll
    for (int r = 0; r < 4; ++r) {
        int nl = w * 16 + quad * 4 + r;
        sOut[nl * 16 + m] = (_Float16)acc[r];
    }
    __syncthreads();
    int nn = t >> 2, ch = t & 3;
    int gn = row0 + nn;
    if (gn < N)
        *(float2*)&hw1h[(size_t)gn * 16 + ch * 4] = *(float2*)&sOut[nn * 16 + ch * 4];
}

// layer-1 (exact R5): 4 lanes/node, quad-split edge list, 2-deep index
// prefetch, masked full-width final chunk, shfl_xor butterfly merge, fused
// register GEMM2 (lane j -> out dims 2j,2j+1) -> hw2h (fp16, dinv-prescaled).
__global__ __launch_bounds__(256) void k_agg1c(const int* __restrict__ rowstart,
                                               const int* __restrict__ rowend,
                                               const int* __restrict__ csr_src,
                                               const f16x8* __restrict__ hw1v,
                                               const float* __restrict__ W2,
                                               const float* __restrict__ b1,
                                               __half* __restrict__ hw2h, int N) {
    __shared__ float sW[128], sb[16];
    int t = threadIdx.x;
    if (t < 128) sW[t] = W2[t];
    if (t < 16)  sb[t] = b1[t];
    __syncthreads();
    int q = t >> 2, j = t & 3;
    int i = blockIdx.x * 64 + q;
    if (i >= N) return;
    int beg = rowstart[i], end = rowend[i];
    int deg = end - beg;
    float di = rsqrtf((float)(deg + 1));
    float a[16];
#pragma unroll
    for (int d = 0; d < 16; ++d) a[d] = 0.f;
    int nfull = deg >> 4;
    int base0 = beg + 4 * j;
    int s4[4];
    if (nfull > 0) {
#pragma unroll
        for (int m = 0; m < 4; ++m) s4[m] = csr_src[base0 + m];
    }
    for (int ch = 0; ch < nfull; ++ch) {
        f16x8 lo[4], hi[4];
#pragma unroll
        for (int m = 0; m < 4; ++m) {
            lo[m] = hw1v[2 * (size_t)s4[m]];
            hi[m] = hw1v[2 * (size_t)s4[m] + 1];
        }
        int sn[4];
        if (ch + 1 < nfull) {      // prefetch next chunk's indices under gathers
#pragma unroll
            for (int m = 0; m < 4; ++m) sn[m] = csr_src[base0 + (ch + 1) * 16 + m];
        }
#pragma unroll
        for (int m = 0; m < 4; ++m) {
#pragma unroll
            for (int d = 0; d < 8; ++d) {
                a[d]     += (float)lo[m][d];
                a[8 + d] += (float)hi[m][d];
            }
        }
        if (ch + 1 < nfull) {
#pragma unroll
            for (int m = 0; m < 4; ++m) s4[m] = sn[m];
        }
    }
    if (deg & 15) {                // masked full-width final chunk
        int cb = beg + nfull * 16 + 4 * j;
        int   sr[4];
        float wr[4];
#pragma unroll
        for (int m = 0; m < 4; ++m) {
            int c = cb + m;
            bool ok = c < end;
            sr[m] = ok ? csr_src[c] : i;   // dummy = self row (hot line), weight 0
            wr[m] = ok ? 1.f : 0.f;
        }
        f16x8 lo[4], hi[4];
#pragma unroll
        for (int m = 0; m < 4; ++m) {
            lo[m] = hw1v[2 * (size_t)sr[m]];
            hi[m] = hw1v[2 * (size_t)sr[m] + 1];
        }
#pragma unroll
        for (int m = 0; m < 4; ++m) {
#pragma unroll
            for (int d = 0; d < 8; ++d) {
                a[d]     += wr[m] * (float)lo[m][d];
                a[8 + d] += wr[m] * (float)hi[m][d];
            }
        }
    }
    if (j == 0) {   // self loop (once per node)
        f16x8 lo = hw1v[2 * (size_t)i];
        f16x8 hi = hw1v[2 * (size_t)i + 1];
#pragma unroll
        for (int d = 0; d < 8; ++d) {
            a[d]     += (float)lo[d];
            a[8 + d] += (float)hi[d];
        }
    }
    // butterfly merge across the quad
#pragma unroll
    for (int d = 0; d < 16; ++d) a[d] += __shfl_xor(a[d], 1, 4);
#pragma unroll
    for (int d = 0; d < 16; ++d) a[d] += __shfl_xor(a[d], 2, 4);
    // fused GEMM2: lane j computes output dims 2j, 2j+1
    float o0 = 0.f, o1 = 0.f;
#pragma unroll
    for (int k = 0; k < 16; ++k) {
        float hv = di * a[k] + sb[k];
        o0 += hv * sW[k * 8 + 2 * j];
        o1 += hv * sW[k * 8 + 2 * j + 1];
    }
    f16x2 ho = {(_Float16)(di * o0), (_Float16)(di * o1)};
    *(f16x2*)&hw2h[(size_t)i * 8 + 2 * j] = ho;   // 4B store, 16B/node across quad
}

// layer-2 (exact R5): 4 lanes/node, 8-dim accumulator, prefetch + masked
// final chunk, butterfly merge, Wl dot + sigmoid.
__global__ __launch_bounds__(256) void k_agg2c(const int* __restrict__ rowstart,
                                               const int* __restrict__ rowend,
                                               const int* __restrict__ csr_src,
                                               const f16x8* __restrict__ hw2v,
                                               const float* __restrict__ Wl,
                                               const float* __restrict__ b2,
                                               const float* __restrict__ bl,
                                               float* __restrict__ z, int N) {
    __shared__ float sW[8], sb[8], sbl;
    int t = threadIdx.x;
    if (t < 8) { sW[t] = Wl[t]; sb[t] = b2[t]; }
    if (t == 0) sbl = bl[0];
    __syncthreads();
    int q = t >> 2, j = t & 3;
    int i = blockIdx.x * 64 + q;
    if (i >= N) return;
    int beg = rowstart[i], end = rowend[i];
    int deg = end - beg;
    float di = rsqrtf((float)(deg + 1));
    float a[8];
#pragma unroll
    for (int d = 0; d < 8; ++d) a[d] = 0.f;
    int nfull = deg >> 4;
    int base0 = beg + 4 * j;
    int s4[4];
    if (nfull > 0) {
#pragma unroll
        for (int m = 0; m < 4; ++m) s4[m] = csr_src[base0 + m];
    }
    for (int ch = 0; ch < nfull; ++ch) {
        f16x8 gv[4];
#pragma unroll
        for (int m = 0; m < 4; ++m) gv[m] = hw2v[(size_t)s4[m]];
        int sn[4];
        if (ch + 1 < nfull) {
#pragma unroll
            for (int m = 0; m < 4; ++m) sn[m] = csr_src[base0 + (ch + 1) * 16 + m];
        }
#pragma unroll
        for (int m = 0; m < 4; ++m)
#pragma unroll
            for (int d = 0; d < 8; ++d) a[d] += (float)gv[m][d];
        if (ch + 1 < nfull) {
#pragma unroll
            for (int m = 0; m < 4; ++m) s4[m] = sn[m];
        }
    }
    if (deg & 15) {
        int cb = beg + nfull * 16 + 4 * j;
        int   sr[4];
        float wr[4];
#pragma unroll
        for (int m = 0; m < 4; ++m) {
            int c = cb + m;
            bool ok = c < end;
            sr[m] = ok ? csr_src[c] : i;
            wr[m] = ok ? 1.f : 0.f;
        }
        f16x8 gv[4];
#pragma unroll
        for (int m = 0; m < 4; ++m) gv[m] = hw2v[(size_t)sr[m]];
#pragma unroll
        for (int m = 0; m < 4; ++m)
#pragma unroll
            for (int d = 0; d < 8; ++d) a[d] += wr[m] * (float)gv[m][d];
    }
    if (j == 0) {
        f16x8 self = hw2v[(size_t)i];
#pragma unroll
        for (int d = 0; d < 8; ++d) a[d] += (float)self[d];
    }
#pragma unroll
    for (int d = 0; d < 8; ++d) a[d] += __shfl_xor(a[d], 1, 4);
#pragma unroll
    for (int d = 0; d < 8; ++d) a[d] += __shfl_xor(a[d], 2, 4);
    if (j == 0) {
        float v = 0.f;
#pragma unroll
        for (int d = 0; d < 8; ++d) {
            float h = di * a[d] + sb[d];
            v += h * sW[d];
        }
        z[i] = 1.f / (1.f + __expf(-(v + sbl)));
    }
}

__global__ __launch_bounds__(256) void k_pred(const int2* __restrict__ pe2,
                                              const float* __restrict__ z,
                                              float* __restrict__ out, int P) {
    int p = blockIdx.x * 256 + threadIdx.x;
    if (p < P) {
        int2 e = pe2[p];
        out[p] = z[e.x] * z[e.y];
    }
}

// ---------------- launch ----------------

extern "C" void kernel_launch(void* const* d_in, const int* in_sizes, int n_in,
                              void* d_out, int out_size, void* d_ws, size_t ws_size,
                              hipStream_t stream) {
    const float* x  = (const float*)d_in[0];
    const int*   ei = (const int*)d_in[1];
    const int*   pe = (const int*)d_in[2];
    const float* W1 = (const float*)d_in[3];
    const float* b1 = (const float*)d_in[4];
    const float* W2 = (const float*)d_in[5];
    const float* b2 = (const float*)d_in[6];
    const float* Wl = (const float*)d_in[7];
    const float* bl = (const float*)d_in[8];
    float* out = (float*)d_out;

    const int N = in_sizes[0] / 128;
    const int E = in_sizes[1] / 2;
    const int P = in_sizes[2] / 2;
    const int NBUK = (N + BUCK - 1) >> BSHIFT;   // 391 for N=100000

    const int* src = ei;
    const int* dst = ei + E;

    // workspace (4B words), ~45 MB:
    float*  ws   = (float*)d_ws;
    float*  dinv = ws;                               // N
    __half* hw1h = (__half*)(ws + (size_t)N);        // 16N halves = 8N words (16B-aligned)
    __half* hw2h = (__half*)(ws + (size_t)9 * N);    // 8N halves = 4N words
    float*  z    = ws + (size_t)13 * N;              // N
    int* rowstart = (int*)(ws + (size_t)14 * N);     // N
    int* rowend   = rowstart + N;                    // N
    int* bcursor  = rowend + N;                      // NBUK
    int* binned   = bcursor + 512;                   // NBUK*CAP (sparse)
    int* csr_src  = binned + (size_t)NBUK * CAP;     // NBUK*CAP (sparse)

    const int B = 256;

    // R12 order: gemm1's 51 MB x-stream runs FIRST so it cannot evict the
    // CSR build's outputs before the gather kernels consume them.
    k_gemm1<<<(N + 63) / 64, B, 0, stream>>>(x, W1, hw1h, N);
    k_curinit<<<(NBUK + B - 1) / B, B, 0, stream>>>(bcursor, NBUK);
    k_binscatter<<<(E + TILE - 1) / TILE, 1024, 0, stream>>>(src, dst, bcursor, binned, E, NBUK);
    k_sortbucket<<<NBUK, 1024, 0, stream>>>(bcursor, binned, csr_src, rowstart, rowend,
                                            dinv, hw1h, N);
    k_agg1c<<<(N + 63) / 64, B, 0, stream>>>(rowstart, rowend, csr_src,
                                             (const f16x8*)hw1h, W2, b1, hw2h, N);
    k_agg2c<<<(N + 63) / 64, B, 0, stream>>>(rowstart, rowend, csr_src,
                                             (const f16x8*)hw2h, Wl, b2, bl, z, N);
    k_pred<<<(P + B - 1) / B, B, 0, stream>>>((const int2*)pe, z, out, P);
}

// Round 14
// 194.029 us; speedup vs baseline: 1.0012x; 1.0012x over previous
//
#include <hip/hip_runtime.h>
#include <hip/hip_fp16.h>
#include <math.h>

// Fixed-capacity bucketed CSR build (per-tile LDS counting sort -> coalesced
// bucket writes), then node-parallel coalesced gather aggregation with fp16
// gather tables (hw1h 3.2 MB, hw2h 1.6 MB).
// R1: wave-shuffle scans. R3: quad-split agg. R5: masked tails + idx prefetch.
// R10: LDS-staged sortbucket scatter (-10.8). R11: rank capture (-2.5).
// R12: gemm1 unscaled+first; sortbucket scales hw1h in epilogue (neutral,
//      kept: enables degree-free gemm1).
// R13: (a) k_curinit ELIMINATED -> hipMemsetAsync(bcursor,0) + gbase =
//      b*CAP + atomicAdd (one fewer launch); (b) agg kernels 8 lanes/node
//      (32-edge chunks): mean deg 32 -> ONE full chunk + masked tail, the
//      dependent idx->gather chain halves vs 4-lane.
// R14: resubmit of R13 unchanged (R13 bench was an infra failure, no data).
#define BSHIFT 8
#define BUCK   256
#define TILE   8192     // edges per scatter workgroup (1024 threads, 8 edges/thread)
#define CAP    12288    // bucket capacity; mean 8184, sigma 90 -> 45 sigma headroom

typedef _Float16 f16x2 __attribute__((ext_vector_type(2)));
typedef _Float16 f16x4 __attribute__((ext_vector_type(4)));
typedef _Float16 f16x8 __attribute__((ext_vector_type(8)));
typedef float    f32x4 __attribute__((ext_vector_type(4)));

// ---------------- CSR build ----------------

// tile scatter with full per-tile LDS counting sort by bucket, so the global
// binned[] writes are lane-consecutive (coalesced bursts per bucket run).
// packed edge = (dst&255)<<17 | src   (src < 2^17)
// R11: single atomic pass — histogram atomicAdd returns per-edge rank.
// R13: bcursor is zero-initialized (memset); holds per-bucket COUNT.
__global__ __launch_bounds__(1024) void k_binscatter(const int* __restrict__ src,
                                                     const int* __restrict__ dst,
                                                     int* __restrict__ bcursor,
                                                     int* __restrict__ binned, int E, int nbuk) {
    __shared__ int            payload[TILE];   // 32 KB
    __shared__ unsigned short bid16[TILE];     // 16 KB
    __shared__ int cnt[512];                   // histogram
    __shared__ int lstart[512];                // exclusive scan (local base)
    __shared__ int gbase[512];                 // reserved global base
    __shared__ int wsum[8];
    int t = threadIdx.x;
    int tile0 = blockIdx.x * TILE;
    int tileE = min(TILE, E - tile0);
    if (t < 512) cnt[t] = 0;
    __syncthreads();
    // load 8 edges/thread (vectorized when full)
    int d[8], s[8];
    int base = t * 8;
    if (base + 8 <= tileE) {
        const int4* d4 = (const int4*)(dst + tile0 + base);
        const int4* s4 = (const int4*)(src + tile0 + base);
        int4 da = d4[0], db = d4[1];
        int4 sa = s4[0], sb = s4[1];
        d[0] = da.x; d[1] = da.y; d[2] = da.z; d[3] = da.w;
        d[4] = db.x; d[5] = db.y; d[6] = db.z; d[7] = db.w;
        s[0] = sa.x; s[1] = sa.y; s[2] = sa.z; s[3] = sa.w;
        s[4] = sb.x; s[5] = sb.y; s[6] = sb.z; s[7] = sb.w;
    } else {
#pragma unroll
        for (int q = 0; q < 8; ++q) {
            int idx = base + q;
            if (idx < tileE) { d[q] = dst[tile0 + idx]; s[q] = src[tile0 + idx]; }
            else d[q] = -1;
        }
    }
    int rank[8];                               // rank within bucket (free!)
#pragma unroll
    for (int q = 0; q < 8; ++q)
        if (d[q] >= 0) rank[q] = atomicAdd(&cnt[d[q] >> BSHIFT], 1);
    __syncthreads();
    // wave-shuffle exclusive scan over cnt[512]: 8 full waves scan 64 each,
    // thread 0 combines wave sums.
    int c = 0, ex = 0;
    if (t < 512) {
        c = cnt[t];
        int v = c;
#pragma unroll
        for (int off = 1; off < 64; off <<= 1) {
            int u = __shfl_up(v, off, 64);
            if ((t & 63) >= off) v += u;
        }
        if ((t & 63) == 63) wsum[t >> 6] = v;
        ex = v - c;
    }
    __syncthreads();
    if (t == 0) {
        int run = 0;
#pragma unroll
        for (int w = 0; w < 8; ++w) { int u = wsum[w]; wsum[w] = run; run += u; }
    }
    __syncthreads();
    if (t < 512) {
        ex += wsum[t >> 6];
        // bcursor holds COUNT (zero-initialized by memset); global base =
        // bucket origin + reserved offset.
        gbase[t] = t * CAP + (c ? atomicAdd(&bcursor[t], c) : 0);
        lstart[t] = ex;                                  // local base
    }
    __syncthreads();
    // LDS scatter WITHOUT atomics: position = lstart[b] + rank
#pragma unroll
    for (int q = 0; q < 8; ++q) {
        if (d[q] >= 0) {
            int b = d[q] >> BSHIFT;
            int lp = lstart[b] + rank[q];
            payload[lp] = ((d[q] & (BUCK - 1)) << 17) | s[q];
            bid16[lp] = (unsigned short)b;
        }
    }
    __syncthreads();
    // coalesced copy-out: consecutive k -> consecutive global addresses
    for (int k = t; k < tileE; k += 1024) {
        int b = bid16[k];
        int ga = gbase[b] + (k - lstart[b]);
        if (ga < (b + 1) * CAP)                          // overflow guard (45 sigma)
            binned[ga] = payload[k];
    }
}

// per-bucket counting sort -> csr_src (dst-sorted, sparse layout), rowstart/
// rowend, dinv. R10: LDS-staged scatter + coalesced copy-out. R11: rank
// capture. R12: epilogue scales hw1h rows by dinv (gemm1 runs first,
// unscaled). R13: bcursor[b] is a count.
__global__ __launch_bounds__(1024) void k_sortbucket(const int* __restrict__ bcursor,
                                                     const int* __restrict__ binned,
                                                     int* __restrict__ csr_src,
                                                     int* __restrict__ rowstart,
                                                     int* __restrict__ rowend,
                                                     float* __restrict__ dinv,
                                                     __half* __restrict__ hw1h, int N) {
    __shared__ int sp[CAP];          // 48 KB sorted payload stage
    __shared__ int cnt[BUCK];
    __shared__ int excl[BUCK];
    __shared__ int wsum[4];
    int b = blockIdx.x, t = threadIdx.x;
    if (t < BUCK) cnt[t] = 0;
    __syncthreads();
    int beg = b * CAP;
    int end = beg + min(bcursor[b], CAP);
    int tot = end - beg;
    int v[12];
#pragma unroll
    for (int q = 0; q < 12; ++q) {
        int e = beg + q * 1024 + t;
        v[q] = (e < end) ? binned[e] : -1;
    }
    int rk[12];                      // rank within node (free from histogram)
#pragma unroll
    for (int q = 0; q < 12; ++q)
        if (v[q] >= 0) rk[q] = atomicAdd(&cnt[v[q] >> 17], 1);
    __syncthreads();
    // wave-shuffle exclusive scan over cnt[256] (4 full waves + combine)
    int c = 0, ex = 0;
    if (t < BUCK) {
        c = cnt[t];
        int s = c;
#pragma unroll
        for (int off = 1; off < 64; off <<= 1) {
            int u = __shfl_up(s, off, 64);
            if ((t & 63) >= off) s += u;
        }
        if ((t & 63) == 63) wsum[t >> 6] = s;
        ex = s - c;
    }
    __syncthreads();
    if (t == 0) {
        int run = 0;
#pragma unroll
        for (int w = 0; w < 4; ++w) { int u = wsum[w]; wsum[w] = run; run += u; }
    }
    __syncthreads();
    if (t < BUCK) {
        ex += wsum[t >> 6];
        excl[t] = ex;
        int node = b * BUCK + t;
        if (node < N) {
            rowstart[node] = beg + ex;
            rowend[node]   = beg + ex + c;
            float di = rsqrtf((float)(c + 1));   // +1 self loop
            dinv[node] = di;
            // R12: scale this node's hw1h row in place (gemm1 wrote unscaled)
            f16x8* row = (f16x8*)&hw1h[(size_t)node * 16];
            f16x8 lo = row[0], hi = row[1];
            _Float16 dh = (_Float16)di;
#pragma unroll
            for (int d = 0; d < 8; ++d) { lo[d] = lo[d] * dh; hi[d] = hi[d] * dh; }
            row[0] = lo; row[1] = hi;
        }
    }
    __syncthreads();
    // LDS scatter WITHOUT atomics: pos = excl[node] + rank
#pragma unroll
    for (int q = 0; q < 12; ++q) {
        if (v[q] >= 0) {
            int pos = excl[v[q] >> 17] + rk[q];
            sp[pos] = v[q] & 0x1FFFF;              // pos < tot <= CAP
        }
    }
    __syncthreads();
    for (int k = t; k < tot; k += 1024)            // coalesced copy-out
        csr_src[beg + k] = sp[k];
}

// ---------------- layer compute ----------------

// hw1h[i,:] = fp16( x[i,:] @ W1 )  UNSCALED via MFMA 16x16x32 f16.
// (dinv scaling applied later by sortbucket's epilogue.)
__global__ __launch_bounds__(256) void k_gemm1(const float* __restrict__ x,
                                               const float* __restrict__ W1,
                                               __half* __restrict__ hw1h, int N) {
    __shared__ _Float16 sX[64 * 136];   // x tile fp16, row pad 136
    __shared__ _Float16 sW[16 * 136];   // W1^T fp16
    __shared__ _Float16 sOut[64 * 16];
    int t = threadIdx.x;
    int row0 = blockIdx.x * 64;
    for (int e = t; e < 2048; e += 256) {
        int n = e & 15, k = e >> 4;
        sW[n * 136 + k] = (_Float16)W1[k * 16 + n];
    }
    const float4* x4 = (const float4*)x;
#pragma unroll
    for (int q = 0; q < 8; ++q) {
        int e = q * 256 + t;
        int r = e >> 5, c4 = e & 31;
        int gr = row0 + r;
        float4 v = (gr < N) ? x4[(size_t)gr * 32 + c4] : make_float4(0.f, 0.f, 0.f, 0.f);
        f16x4 hv = {(_Float16)v.x, (_Float16)v.y, (_Float16)v.z, (_Float16)v.w};
        *(f16x4*)&sX[r * 136 + c4 * 4] = hv;   // one ds_write_b64 (8B-aligned)
    }
    __syncthreads();
    int w = t >> 6, l = t & 63;
    int m = l & 15, quad = l >> 4;
    f32x4 acc = {0.f, 0.f, 0.f, 0.f};
#pragma unroll
    for (int kc = 0; kc < 4; ++kc) {
        f16x8 a = *(const f16x8*)&sX[(w * 16 + m) * 136 + kc * 32 + quad * 8];
        f16x8 b = *(const f16x8*)&sW[m * 136 + kc * 32 + quad * 8];
        acc = __builtin_amdgcn_mfma_f32_16x16x32_f16(a, b, acc, 0, 0, 0);
    }
#pragma unroll
    for (int r = 0; r < 4; ++r) {
        int nl = w * 16 + quad * 4 + r;
        sOut[nl * 16 + m] = (_Float16)acc[r];
    }
    __syncthreads();
    int nn = t >> 2, ch = t & 3;
    int gn = row0 + nn;
    if (gn < N)
        *(float2*)&hw1h[(size_t)gn * 16 + ch * 4] = *(float2*)&sOut[nn * 16 + ch * 4];
}

// layer-1 (R13): 8 lanes/node, 32-edge chunks (4 edges/lane), 2-deep index
// prefetch, masked full-width final chunk, 3-step shfl_xor butterfly, fused
// register GEMM2 (lane j -> out dim j) -> hw2h (fp16, dinv-prescaled).
__global__ __launch_bounds__(256) void k_agg1c(const int* __restrict__ rowstart,
                                               const int* __restrict__ rowend,
                                               const int* __restrict__ csr_src,
                                               const f16x8* __restrict__ hw1v,
                                               const float* __restrict__ W2,
                                               const float* __restrict__ b1,
                                               __half* __restrict__ hw2h, int N) {
    __shared__ float sW[128], sb[16];
    int t = threadIdx.x;
    if (t < 128) sW[t] = W2[t];
    if (t < 16)  sb[t] = b1[t];
    __syncthreads();
    int q = t >> 3, j = t & 7;
    int i = blockIdx.x * 32 + q;
    if (i >= N) return;
    int beg = rowstart[i], end = rowend[i];
    int deg = end - beg;
    float di = rsqrtf((float)(deg + 1));
    float a[16];
#pragma unroll
    for (int d = 0; d < 16; ++d) a[d] = 0.f;
    int nfull = deg >> 5;                  // 32-edge chunks
    int base0 = beg + 4 * j;
    int s4[4];
    if (nfull > 0) {
#pragma unroll
        for (int m = 0; m < 4; ++m) s4[m] = csr_src[base0 + m];
    }
    for (int ch = 0; ch < nfull; ++ch) {
        f16x8 lo[4], hi[4];
#pragma unroll
        for (int m = 0; m < 4; ++m) {
            lo[m] = hw1v[2 * (size_t)s4[m]];
            hi[m] = hw1v[2 * (size_t)s4[m] + 1];
        }
        int sn[4];
        if (ch + 1 < nfull) {      // prefetch next chunk's indices under gathers
#pragma unroll
            for (int m = 0; m < 4; ++m) sn[m] = csr_src[base0 + (ch + 1) * 32 + m];
        }
#pragma unroll
        for (int m = 0; m < 4; ++m) {
#pragma unroll
            for (int d = 0; d < 8; ++d) {
                a[d]     += (float)lo[m][d];
                a[8 + d] += (float)hi[m][d];
            }
        }
        if (ch + 1 < nfull) {
#pragma unroll
            for (int m = 0; m < 4; ++m) s4[m] = sn[m];
        }
    }
    if (deg & 31) {                // masked full-width final chunk
        int cb = beg + nfull * 32 + 4 * j;
        int   sr[4];
        float wr[4];
#pragma unroll
        for (int m = 0; m < 4; ++m) {
            int c = cb + m;
            bool ok = c < end;
            sr[m] = ok ? csr_src[c] : i;   // dummy = self row (hot line), weight 0
            wr[m] = ok ? 1.f : 0.f;
        }
        f16x8 lo[4], hi[4];
#pragma unroll
        for (int m = 0; m < 4; ++m) {
            lo[m] = hw1v[2 * (size_t)sr[m]];
            hi[m] = hw1v[2 * (size_t)sr[m] + 1];
        }
#pragma unroll
        for (int m = 0; m < 4; ++m) {
#pragma unroll
            for (int d = 0; d < 8; ++d) {
                a[d]     += wr[m] * (float)lo[m][d];
                a[8 + d] += wr[m] * (float)hi[m][d];
            }
        }
    }
    if (j == 0) {   // self loop (once per node)
        f16x8 lo = hw1v[2 * (size_t)i];
        f16x8 hi = hw1v[2 * (size_t)i + 1];
#pragma unroll
        for (int d = 0; d < 8; ++d) {
            a[d]     += (float)lo[d];
            a[8 + d] += (float)hi[d];
        }
    }
    // butterfly merge across the 8-lane group
#pragma unroll
    for (int d = 0; d < 16; ++d) a[d] += __shfl_xor(a[d], 1, 8);
#pragma unroll
    for (int d = 0; d < 16; ++d) a[d] += __shfl_xor(a[d], 2, 8);
#pragma unroll
    for (int d = 0; d < 16; ++d) a[d] += __shfl_xor(a[d], 4, 8);
    // fused GEMM2: lane j computes output dim j
    float o = 0.f;
#pragma unroll
    for (int k = 0; k < 16; ++k) {
        float hv = di * a[k] + sb[k];
        o += hv * sW[k * 8 + j];
    }
    hw2h[(size_t)i * 8 + j] = (__half)(di * o);   // 2B store, 16B/node across group
}

// layer-2 (R13): 8 lanes/node, 8-dim accumulator, 32-edge chunks, prefetch +
// masked final chunk, butterfly merge, Wl dot + sigmoid.
__global__ __launch_bounds__(256) void k_agg2c(const int* __restrict__ rowstart,
                                               const int* __restrict__ rowend,
                                               const int* __restrict__ csr_src,
                                               const f16x8* __restrict__ hw2v,
                                               const float* __restrict__ Wl,
                                               const float* __restrict__ b2,
                                               const float* __restrict__ bl,
                                               float* __restrict__ z, int N) {
    __shared__ float sW[8], sb[8], sbl;
    int t = threadIdx.x;
    if (t < 8) { sW[t] = Wl[t]; sb[t] = b2[t]; }
    if (t == 0) sbl = bl[0];
    __syncthreads();
    int q = t >> 3, j = t & 7;
    int i = blockIdx.x * 32 + q;
    if (i >= N) return;
    int beg = rowstart[i], end = rowend[i];
    int deg = end - beg;
    float di = rsqrtf((float)(deg + 1));
    float a[8];
#pragma unroll
    for (int d = 0; d < 8; ++d) a[d] = 0.f;
    int nfull = deg >> 5;
    int base0 = beg + 4 * j;
    int s4[4];
    if (nfull > 0) {
#pragma unroll
        for (int m = 0; m < 4; ++m) s4[m] = csr_src[base0 + m];
    }
    for (int ch = 0; ch < nfull; ++ch) {
        f16x8 gv[4];
#pragma unroll
        for (int m = 0; m < 4; ++m) gv[m] = hw2v[(size_t)s4[m]];
        int sn[4];
        if (ch + 1 < nfull) {
#pragma unroll
            for (int m = 0; m < 4; ++m) sn[m] = csr_src[base0 + (ch + 1) * 32 + m];
        }
#pragma unroll
        for (int m = 0; m < 4; ++m)
#pragma unroll
            for (int d = 0; d < 8; ++d) a[d] += (float)gv[m][d];
        if (ch + 1 < nfull) {
#pragma unroll
            for (int m = 0; m < 4; ++m) s4[m] = sn[m];
        }
    }
    if (deg & 31) {
        int cb = beg + nfull * 32 + 4 * j;
        int   sr[4];
        float wr[4];
#pragma unroll
        for (int m = 0; m < 4; ++m) {
            int c = cb + m;
            bool ok = c < end;
            sr[m] = ok ? csr_src[c] : i;
            wr[m] = ok ? 1.f : 0.f;
        }
        f16x8 gv[4];
#pragma unroll
        for (int m = 0; m < 4; ++m) gv[m] = hw2v[(size_t)sr[m]];
#pragma unroll
        for (int m = 0; m < 4; ++m)
#pragma unroll
            for (int d = 0; d < 8; ++d) a[d] += wr[m] * (float)gv[m][d];
    }
    if (j == 0) {
        f16x8 self = hw2v[(size_t)i];
#pragma unroll
        for (int d = 0; d < 8; ++d) a[d] += (float)self[d];
    }
#pragma unroll
    for (int d = 0; d < 8; ++d) a[d] += __shfl_xor(a[d], 1, 8);
#pragma unroll
    for (int d = 0; d < 8; ++d) a[d] += __shfl_xor(a[d], 2, 8);
#pragma unroll
    for (int d = 0; d < 8; ++d) a[d] += __shfl_xor(a[d], 4, 8);
    if (j == 0) {
        float v = 0.f;
#pragma unroll
        for (int d = 0; d < 8; ++d) {
            float h = di * a[d] + sb[d];
            v += h * sW[d];
        }
        z[i] = 1.f / (1.f + __expf(-(v + sbl)));
    }
}

__global__ __launch_bounds__(256) void k_pred(const int2* __restrict__ pe2,
                                              const float* __restrict__ z,
                                              float* __restrict__ out, int P) {
    int p = blockIdx.x * 256 + threadIdx.x;
    if (p < P) {
        int2 e = pe2[p];
        out[p] = z[e.x] * z[e.y];
    }
}

// ---------------- launch ----------------

extern "C" void kernel_launch(void* const* d_in, const int* in_sizes, int n_in,
                              void* d_out, int out_size, void* d_ws, size_t ws_size,
                              hipStream_t stream) {
    const float* x  = (const float*)d_in[0];
    const int*   ei = (const int*)d_in[1];
    const int*   pe = (const int*)d_in[2];
    const float* W1 = (const float*)d_in[3];
    const float* b1 = (const float*)d_in[4];
    const float* W2 = (const float*)d_in[5];
    const float* b2 = (const float*)d_in[6];
    const float* Wl = (const float*)d_in[7];
    const float* bl = (const float*)d_in[8];
    float* out = (float*)d_out;

    const int N = in_sizes[0] / 128;
    const int E = in_sizes[1] / 2;
    const int P = in_sizes[2] / 2;
    const int NBUK = (N + BUCK - 1) >> BSHIFT;   // 391 for N=100000

    const int* src = ei;
    const int* dst = ei + E;

    // workspace (4B words), ~45 MB:
    float*  ws   = (float*)d_ws;
    float*  dinv = ws;                               // N
    __half* hw1h = (__half*)(ws + (size_t)N);        // 16N halves = 8N words (16B-aligned)
    __half* hw2h = (__half*)(ws + (size_t)9 * N);    // 8N halves = 4N words
    float*  z    = ws + (size_t)13 * N;              // N
    int* rowstart = (int*)(ws + (size_t)14 * N);     // N
    int* rowend   = rowstart + N;                    // N
    int* bcursor  = rowend + N;                      // 512 slots (counts)
    int* binned   = bcursor + 512;                   // NBUK*CAP (sparse)
    int* csr_src  = binned + (size_t)NBUK * CAP;     // NBUK*CAP (sparse)

    const int B = 256;

    // R13: curinit kernel replaced by a memset node (bcursor = counts).
    hipMemsetAsync(bcursor, 0, 512 * sizeof(int), stream);
    // R12 order: gemm1's 51 MB x-stream first; sortbucket scales hw1h later.
    k_gemm1<<<(N + 63) / 64, B, 0, stream>>>(x, W1, hw1h, N);
    k_binscatter<<<(E + TILE - 1) / TILE, 1024, 0, stream>>>(src, dst, bcursor, binned, E, NBUK);
    k_sortbucket<<<NBUK, 1024, 0, stream>>>(bcursor, binned, csr_src, rowstart, rowend,
                                            dinv, hw1h, N);
    k_agg1c<<<(N + 31) / 32, B, 0, stream>>>(rowstart, rowend, csr_src,
                                             (const f16x8*)hw1h, W2, b1, hw2h, N);
    k_agg2c<<<(N + 31) / 32, B, 0, stream>>>(rowstart, rowend, csr_src,
                                             (const f16x8*)hw2h, Wl, b2, bl, z, N);
    k_pred<<<(P + B - 1) / B, B, 0, stream>>>((const int2*)pe, z, out, P);
}